// Round 2
// baseline (4237.756 us; speedup 1.0000x reference)
//
#include <hip/hip_runtime.h>
#include <math.h>

#define BB 128
#define SS 128
#define AE 65
#define VE 65
#define TE 129
#define PFD 128
#define FUSED 545025UL
#define PLANE (VE * TE)   // 8385

// ---------------- zero-init accumulators ----------------
__global__ __launch_bounds__(256) void k_zero(float* __restrict__ p, int n) {
  int i = blockIdx.x * 256 + threadIdx.x;
  if (i < n) p[i] = 0.f;
}

// ---------------- core: fusion[b][a][v][w], a,v>=1, w>=1 ----------------
// grid (BB, 32): a-pair = (1+2p, 2+2p). 256 thr: tv=tid>>4 (16), tw=tid&15 (16).
// per-thread tile: 2a x 4v x 8w; v = 1+4tv+i, w = 1+8tw+j.
__global__ __launch_bounds__(256, 4) void k_core(
    const float* __restrict__ audio, const float* __restrict__ vision,
    const float* __restrict__ text, float* __restrict__ F,
    float* __restrict__ normsq)
{
  const int b = blockIdx.x;
  const int p = blockIdx.y;
  const int tid = threadIdx.x;
  const int tw = tid & 15, tv = tid >> 4;

  __shared__ float sA[2][16];
  __shared__ float sAV[16][2][64];   // [s][a][v-1]
  __shared__ float sT[16][192];      // [s][12*((w-1)>>3) + ((w-1)&7)]
  __shared__ float sOut[16][132];

  float acc[2][4][8];
#pragma unroll
  for (int aa = 0; aa < 2; ++aa)
#pragma unroll
    for (int i = 0; i < 4; ++i)
#pragma unroll
      for (int j = 0; j < 8; ++j) acc[aa][i][j] = 0.f;

  for (int c = 0; c < 8; ++c) {
    const int s0 = c * 16;
    __syncthreads();   // prev chunk compute done
    if (tid < 16) {
      const float2 a2 = *(const float2*)&audio[((size_t)(b * SS + s0 + tid)) * 64 + 2 * p];
      sA[0][tid] = a2.x;
      sA[1][tid] = a2.y;
    }
    __syncthreads();
    const float* vbase = &vision[((size_t)(b * SS + s0)) * 64];
#pragma unroll
    for (int r = 0; r < 4; ++r) {
      const int e = tid + 256 * r;          // < 1024
      const int s = e >> 6, v = e & 63;
      const float vv = vbase[e];
      sAV[s][0][v] = sA[0][s] * vv;
      sAV[s][1][v] = sA[1][s] * vv;
    }
    const float* tbase = &text[((size_t)(b * SS + s0)) * 128];
#pragma unroll
    for (int r = 0; r < 8; ++r) {
      const int e = tid + 256 * r;          // < 2048
      const int s = e >> 7, w = e & 127;
      sT[s][12 * (w >> 3) + (w & 7)] = tbase[e];
    }
    __syncthreads();
#pragma unroll
    for (int s = 0; s < 16; ++s) {
      const float4 a0 = *(const float4*)&sAV[s][0][4 * tv];
      const float4 a1 = *(const float4*)&sAV[s][1][4 * tv];
      const float4 t0 = *(const float4*)&sT[s][12 * tw];
      const float4 t1 = *(const float4*)&sT[s][12 * tw + 4];
      const float av[2][4] = {{a0.x, a0.y, a0.z, a0.w}, {a1.x, a1.y, a1.z, a1.w}};
      const float tt[8] = {t0.x, t0.y, t0.z, t0.w, t1.x, t1.y, t1.z, t1.w};
#pragma unroll
      for (int aa = 0; aa < 2; ++aa)
#pragma unroll
        for (int i = 0; i < 4; ++i)
#pragma unroll
          for (int j = 0; j < 8; ++j) acc[aa][i][j] += av[aa][i] * tt[j];
    }
  }

  // ||.||^2 contribution (core region only)
  float ss = 0.f;
#pragma unroll
  for (int aa = 0; aa < 2; ++aa)
#pragma unroll
    for (int i = 0; i < 4; ++i)
#pragma unroll
      for (int j = 0; j < 8; ++j) ss += acc[aa][i][j] * acc[aa][i][j];
#pragma unroll
  for (int off = 32; off > 0; off >>= 1) ss += __shfl_down(ss, off);
  if ((tid & 63) == 0) atomicAdd(&normsq[b], ss);

  // write via LDS for coalesced 128-float rows
  for (int aa = 0; aa < 2; ++aa) {
    const int a = 1 + 2 * p + aa;
    float* Fb = F + ((size_t)b * AE + a) * PLANE;
#pragma unroll
    for (int g = 0; g < 4; ++g) {
      __syncthreads();
      *(float4*)&sOut[tv][8 * tw] =
          make_float4(acc[aa][g][0], acc[aa][g][1], acc[aa][g][2], acc[aa][g][3]);
      *(float4*)&sOut[tv][8 * tw + 4] =
          make_float4(acc[aa][g][4], acc[aa][g][5], acc[aa][g][6], acc[aa][g][7]);
      __syncthreads();
#pragma unroll
      for (int r = 0; r < 8; ++r) {
        const int e = tid + 256 * r;        // < 2048
        const int row = e >> 7, wi = e & 127;
        Fb[(size_t)(1 + 4 * row + g) * TE + 1 + wi] = sOut[row][wi];
      }
    }
  }
}

// ---------------- plane a=0: fusion[b][0][v][w] = sum_s v'*t' ----------------
__global__ __launch_bounds__(256, 4) void k_pa(
    const float* __restrict__ vision, const float* __restrict__ text,
    float* __restrict__ F, float* __restrict__ normsq)
{
  const int b = blockIdx.x;
  const int tid = threadIdx.x;
  const int tw = tid & 15, tv = tid >> 4;
  __shared__ float sv[32][80];
  __shared__ float st[32][144];
  float acc[5][9];
#pragma unroll
  for (int i = 0; i < 5; ++i)
#pragma unroll
    for (int j = 0; j < 9; ++j) acc[i][j] = 0.f;

  for (int c = 0; c < 4; ++c) {
    const int s0 = 32 * c;
    __syncthreads();
    const float* vbase = &vision[((size_t)(b * SS + s0)) * 64];
#pragma unroll
    for (int r = 0; r < 8; ++r) {
      const int e = tid + 256 * r;          // < 2048
      sv[e >> 6][(e & 63) + 1] = vbase[e];
    }
    const float* tbase = &text[((size_t)(b * SS + s0)) * 128];
#pragma unroll
    for (int r = 0; r < 16; ++r) {
      const int e = tid + 256 * r;          // < 4096
      st[e >> 7][(e & 127) + 1] = tbase[e];
    }
    if (tid < 32) { sv[tid][0] = 1.f; st[tid][0] = 1.f; }
    __syncthreads();
    for (int s = 0; s < 32; ++s) {
      float vr[5], tr[9];
#pragma unroll
      for (int i = 0; i < 5; ++i) {
        const int vx = tv + 16 * i;
        vr[i] = (vx < VE) ? sv[s][vx] : 0.f;
      }
#pragma unroll
      for (int j = 0; j < 9; ++j) {
        const int wx = tw + 16 * j;
        tr[j] = (wx < TE) ? st[s][wx] : 0.f;
      }
#pragma unroll
      for (int i = 0; i < 5; ++i)
#pragma unroll
        for (int j = 0; j < 9; ++j) acc[i][j] += vr[i] * tr[j];
    }
  }
  float* Fb = F + (size_t)b * AE * PLANE;   // a = 0
  float ss = 0.f;
#pragma unroll
  for (int i = 0; i < 5; ++i) {
    const int v = tv + 16 * i;
    if (v < VE) {
#pragma unroll
      for (int j = 0; j < 9; ++j) {
        const int w = tw + 16 * j;
        if (w < TE) {
          const float m = acc[i][j];
          Fb[(size_t)v * TE + w] = m;
          ss += m * m;
        }
      }
    }
  }
#pragma unroll
  for (int off = 32; off > 0; off >>= 1) ss += __shfl_down(ss, off);
  if ((tid & 63) == 0) atomicAdd(&normsq[b], ss);
}

// ---------------- plane v=0: fusion[b][a][0][w] = sum_s a'*t', a>=1 ----------------
__global__ __launch_bounds__(256, 4) void k_pv(
    const float* __restrict__ audio, const float* __restrict__ text,
    float* __restrict__ F, float* __restrict__ normsq)
{
  const int b = blockIdx.x;
  const int tid = threadIdx.x;
  const int tw = tid & 15, tv = tid >> 4;
  __shared__ float sa[32][64];
  __shared__ float st[32][144];
  float acc[4][9];
#pragma unroll
  for (int i = 0; i < 4; ++i)
#pragma unroll
    for (int j = 0; j < 9; ++j) acc[i][j] = 0.f;

  for (int c = 0; c < 4; ++c) {
    const int s0 = 32 * c;
    __syncthreads();
    const float* abase = &audio[((size_t)(b * SS + s0)) * 64];
#pragma unroll
    for (int r = 0; r < 8; ++r) {
      const int e = tid + 256 * r;
      sa[e >> 6][e & 63] = abase[e];
    }
    const float* tbase = &text[((size_t)(b * SS + s0)) * 128];
#pragma unroll
    for (int r = 0; r < 16; ++r) {
      const int e = tid + 256 * r;
      st[e >> 7][(e & 127) + 1] = tbase[e];
    }
    if (tid < 32) st[tid][0] = 1.f;
    __syncthreads();
    for (int s = 0; s < 32; ++s) {
      float ar[4], tr[9];
#pragma unroll
      for (int i = 0; i < 4; ++i) ar[i] = sa[s][tv + 16 * i];
#pragma unroll
      for (int j = 0; j < 9; ++j) {
        const int wx = tw + 16 * j;
        tr[j] = (wx < TE) ? st[s][wx] : 0.f;
      }
#pragma unroll
      for (int i = 0; i < 4; ++i)
#pragma unroll
        for (int j = 0; j < 9; ++j) acc[i][j] += ar[i] * tr[j];
    }
  }
  float ss = 0.f;
#pragma unroll
  for (int i = 0; i < 4; ++i) {
    const int a = 1 + tv + 16 * i;
    float* Fb = F + ((size_t)b * AE + a) * PLANE;   // v = 0
#pragma unroll
    for (int j = 0; j < 9; ++j) {
      const int w = tw + 16 * j;
      if (w < TE) {
        const float m = acc[i][j];
        Fb[w] = m;
        ss += m * m;
      }
    }
  }
#pragma unroll
  for (int off = 32; off > 0; off >>= 1) ss += __shfl_down(ss, off);
  if ((tid & 63) == 0) atomicAdd(&normsq[b], ss);
}

// ---------------- plane w=0: fusion[b][a][v][0] = sum_s a'*v', a,v>=1 ----------------
__global__ __launch_bounds__(256, 4) void k_pw(
    const float* __restrict__ audio, const float* __restrict__ vision,
    float* __restrict__ F, float* __restrict__ normsq)
{
  const int b = blockIdx.x;
  const int tid = threadIdx.x;
  const int tw = tid & 15, tv = tid >> 4;
  __shared__ float sa[32][64];
  __shared__ float sv[32][64];
  float acc[4][4];
#pragma unroll
  for (int i = 0; i < 4; ++i)
#pragma unroll
    for (int j = 0; j < 4; ++j) acc[i][j] = 0.f;

  for (int c = 0; c < 4; ++c) {
    const int s0 = 32 * c;
    __syncthreads();
    const float* abase = &audio[((size_t)(b * SS + s0)) * 64];
    const float* vbase = &vision[((size_t)(b * SS + s0)) * 64];
#pragma unroll
    for (int r = 0; r < 8; ++r) {
      const int e = tid + 256 * r;
      sa[e >> 6][e & 63] = abase[e];
      sv[e >> 6][e & 63] = vbase[e];
    }
    __syncthreads();
    for (int s = 0; s < 32; ++s) {
      float ar[4], vr[4];
#pragma unroll
      for (int i = 0; i < 4; ++i) ar[i] = sa[s][tv + 16 * i];
#pragma unroll
      for (int j = 0; j < 4; ++j) vr[j] = sv[s][tw + 16 * j];
#pragma unroll
      for (int i = 0; i < 4; ++i)
#pragma unroll
        for (int j = 0; j < 4; ++j) acc[i][j] += ar[i] * vr[j];
    }
  }
  float ss = 0.f;
#pragma unroll
  for (int i = 0; i < 4; ++i) {
    const int a = 1 + tv + 16 * i;
    float* Fb = F + ((size_t)b * AE + a) * PLANE;
#pragma unroll
    for (int j = 0; j < 4; ++j) {
      const int v = 1 + tw + 16 * j;
      const float m = acc[i][j];
      Fb[(size_t)v * TE] = m;                       // w = 0
      ss += m * m;
    }
  }
#pragma unroll
  for (int off = 32; off > 0; off >>= 1) ss += __shfl_down(ss, off);
  if ((tid & 63) == 0) atomicAdd(&normsq[b], ss);
}

// ---------------- deep-K GEMM: y1pre[b][p] += W1[p][k]*F[b][k] ----------------
#define KSPAN 1024
#define KT 16
__global__ __launch_bounds__(256, 4) void k_gemm(
    const float* __restrict__ W1, const float* __restrict__ F,
    float* __restrict__ y1pre)
{
  const size_t k0 = (size_t)blockIdx.x * KSPAN;
  const int tid = threadIdx.x;
  const int tb = tid & 15, tp = tid >> 4;

  __shared__ float sW[KT][132];
  __shared__ float sF[KT][132];

  float acc[8][8];
#pragma unroll
  for (int i = 0; i < 8; ++i)
#pragma unroll
    for (int j = 0; j < 8; ++j) acc[i][j] = 0.f;

  float wv[8], fv[8];
#pragma unroll
  for (int r = 0; r < 8; ++r) {     // prefetch iter 0
    const int e = tid + 256 * r;
    const int row = e >> 4, kk = e & 15;
    const size_t k = k0 + kk;
    const bool ok = k < FUSED;
    wv[r] = ok ? W1[(size_t)row * FUSED + k] : 0.f;
    fv[r] = ok ? F[(size_t)row * FUSED + k] : 0.f;
  }

  const int NIT = KSPAN / KT;       // 64
  for (int it = 0; it < NIT; ++it) {
    __syncthreads();
#pragma unroll
    for (int r = 0; r < 8; ++r) {
      const int e = tid + 256 * r;
      const int row = e >> 4, kk = e & 15;
      sW[kk][row] = wv[r];
      sF[kk][row] = fv[r];
    }
    __syncthreads();
    if (it + 1 < NIT) {
      const size_t kb = k0 + (size_t)(it + 1) * KT;
#pragma unroll
      for (int r = 0; r < 8; ++r) {
        const int e = tid + 256 * r;
        const int row = e >> 4, kk = e & 15;
        const size_t k = kb + kk;
        const bool ok = k < FUSED;
        wv[r] = ok ? W1[(size_t)row * FUSED + k] : 0.f;
        fv[r] = ok ? F[(size_t)row * FUSED + k] : 0.f;
      }
    }
#pragma unroll
    for (int kk = 0; kk < KT; ++kk) {
      const float4 w0 = *(const float4*)&sW[kk][8 * tp];
      const float4 w1 = *(const float4*)&sW[kk][8 * tp + 4];
      const float4 f0 = *(const float4*)&sF[kk][8 * tb];
      const float4 f1 = *(const float4*)&sF[kk][8 * tb + 4];
      const float wr[8] = {w0.x, w0.y, w0.z, w0.w, w1.x, w1.y, w1.z, w1.w};
      const float fr[8] = {f0.x, f0.y, f0.z, f0.w, f1.x, f1.y, f1.z, f1.w};
#pragma unroll
      for (int i = 0; i < 8; ++i)
#pragma unroll
        for (int j = 0; j < 8; ++j) acc[i][j] += wr[i] * fr[j];
    }
  }

  const int rot = (blockIdx.x * 23) & 63;   // spread same-word atomic bursts
  for (int l = 0; l < 64; ++l) {
    const int li = (l + rot) & 63;
    const int i = li & 7, j = li >> 3;
    atomicAdd(&y1pre[(size_t)(8 * tb + j) * PFD + 8 * tp + i], acc[i][j]);
  }
}

// ---------------- finalize: MLP per batch ----------------
__global__ __launch_bounds__(128) void k_final(
    const float* __restrict__ y1pre, const float* __restrict__ b1,
    const float* __restrict__ W2, const float* __restrict__ b2,
    const float* __restrict__ W3, const float* __restrict__ b3,
    float* __restrict__ out)
{
  const int b = blockIdx.x, p = threadIdx.x;
  __shared__ float y1[PFD];
  __shared__ float red[PFD];
  y1[p] = fmaxf(y1pre[(size_t)b * PFD + p] + b1[p], 0.f);
  __syncthreads();
  float s = b2[p];
  for (int k = 0; k < PFD; ++k) s += y1[k] * W2[p * PFD + k];
  const float y2 = fmaxf(s, 0.f);
  red[p] = y2 * W3[p];
  __syncthreads();
  for (int off = 64; off > 0; off >>= 1) {
    if (p < off) red[p] += red[p + off];
    __syncthreads();
  }
  if (p == 0) {
    const float x = red[0] + b3[0];
    out[b] = 6.f / (1.f + expf(-x)) - 3.f;
  }
}

__global__ __launch_bounds__(128) void k_reg(const float* __restrict__ normsq,
                                             float* __restrict__ out)
{
  const int t = threadIdx.x;
  __shared__ float red[BB];
  red[t] = sqrtf(normsq[t]);
  __syncthreads();
  for (int off = 64; off > 0; off >>= 1) {
    if (t < off) red[t] += red[t + off];
    __syncthreads();
  }
  // tmp = sqrt(64*64*128/128) = 64 exactly; mean over B
  if (t == 0) out[BB] = 64.f * red[0] / (float)BB;
}

extern "C" void kernel_launch(void* const* d_in, const int* in_sizes, int n_in,
                              void* d_out, int out_size, void* d_ws, size_t ws_size,
                              hipStream_t stream) {
  const float* audio  = (const float*)d_in[0];
  const float* vision = (const float*)d_in[1];
  const float* text   = (const float*)d_in[2];
  const float* W1     = (const float*)d_in[3];
  const float* b1     = (const float*)d_in[4];
  const float* W2     = (const float*)d_in[5];
  const float* b2     = (const float*)d_in[6];
  const float* W3     = (const float*)d_in[7];
  const float* b3     = (const float*)d_in[8];
  float* out = (float*)d_out;

  // ws layout (known-safe bound from round 1: ws >= 131072 + 279,052,800 B):
  // [y1pre 128*128][normsq 128] ... F (full fusion, fp32) at +128 KB
  float* y1pre  = (float*)d_ws;
  float* normsq = y1pre + BB * PFD;
  float* F = (float*)((char*)d_ws + 131072);

  k_zero<<<65, 256, 0, stream>>>(y1pre, BB * PFD + BB);

  k_core<<<dim3(BB, 32), 256, 0, stream>>>(audio, vision, text, F, normsq);
  k_pa<<<BB, 256, 0, stream>>>(vision, text, F, normsq);
  k_pv<<<BB, 256, 0, stream>>>(audio, text, F, normsq);
  k_pw<<<BB, 256, 0, stream>>>(audio, vision, F, normsq);

  const int nb = (int)((FUSED + KSPAN - 1) / KSPAN);   // 533
  k_gemm<<<nb, 256, 0, stream>>>(W1, F, y1pre);

  k_final<<<BB, PFD, 0, stream>>>(y1pre, b1, W2, b2, W3, b3, out);
  k_reg<<<1, BB, 0, stream>>>(normsq, out);
}

// Round 3
// 1176.770 us; speedup vs baseline: 3.6012x; 3.6012x over previous
//
#include <hip/hip_runtime.h>
#include <math.h>

#define BB 128
#define SS 128
#define AE 65
#define VE 65
#define TE 129
#define PFD 128
#define FUSED 545025UL
#define PLANE (VE * TE)   // 8385

// ---------------- zero-init accumulators ----------------
__global__ __launch_bounds__(256) void k_zero(float* __restrict__ p, int n) {
  int i = blockIdx.x * 256 + threadIdx.x;
  if (i < n) p[i] = 0.f;
}

// ---------------- core: fusion[b][a][v][w], a,v>=1, w>=1 ----------------
// grid (BB, 32): a-pair = (1+2p, 2+2p). 256 thr: tv=tid>>4 (16), tw=tid&15 (16).
// per-thread tile: 2a x 4v x 8w; v = 1+4tv+i, w = 1+8tw+j.
__global__ __launch_bounds__(256) void k_core(
    const float* __restrict__ audio, const float* __restrict__ vision,
    const float* __restrict__ text, float* __restrict__ F,
    float* __restrict__ normsq)
{
  const int b = blockIdx.x;
  const int p = blockIdx.y;
  const int tid = threadIdx.x;
  const int tw = tid & 15, tv = tid >> 4;

  __shared__ float sA[2][16];
  __shared__ float sAV[16][2][64];   // [s][a][v-1]
  __shared__ float sT[16][192];      // [s][12*((w-1)>>3) + ((w-1)&7)]
  __shared__ float sOut[16][132];

  float acc[2][4][8];
#pragma unroll
  for (int aa = 0; aa < 2; ++aa)
#pragma unroll
    for (int i = 0; i < 4; ++i)
#pragma unroll
      for (int j = 0; j < 8; ++j) acc[aa][i][j] = 0.f;

  for (int c = 0; c < 8; ++c) {
    const int s0 = c * 16;
    __syncthreads();   // prev chunk compute done
    if (tid < 16) {
      const float2 a2 = *(const float2*)&audio[((size_t)(b * SS + s0 + tid)) * 64 + 2 * p];
      sA[0][tid] = a2.x;
      sA[1][tid] = a2.y;
    }
    __syncthreads();
    const float* vbase = &vision[((size_t)(b * SS + s0)) * 64];
#pragma unroll
    for (int r = 0; r < 4; ++r) {
      const int e = tid + 256 * r;          // < 1024
      const int s = e >> 6, v = e & 63;
      const float vv = vbase[e];
      sAV[s][0][v] = sA[0][s] * vv;
      sAV[s][1][v] = sA[1][s] * vv;
    }
    const float* tbase = &text[((size_t)(b * SS + s0)) * 128];
#pragma unroll
    for (int r = 0; r < 8; ++r) {
      const int e = tid + 256 * r;          // < 2048
      const int s = e >> 7, w = e & 127;
      sT[s][12 * (w >> 3) + (w & 7)] = tbase[e];
    }
    __syncthreads();
#pragma unroll
    for (int s = 0; s < 16; ++s) {
      const float4 a0 = *(const float4*)&sAV[s][0][4 * tv];
      const float4 a1 = *(const float4*)&sAV[s][1][4 * tv];
      const float4 t0 = *(const float4*)&sT[s][12 * tw];
      const float4 t1 = *(const float4*)&sT[s][12 * tw + 4];
      const float av[2][4] = {{a0.x, a0.y, a0.z, a0.w}, {a1.x, a1.y, a1.z, a1.w}};
      const float tt[8] = {t0.x, t0.y, t0.z, t0.w, t1.x, t1.y, t1.z, t1.w};
#pragma unroll
      for (int aa = 0; aa < 2; ++aa)
#pragma unroll
        for (int i = 0; i < 4; ++i)
#pragma unroll
          for (int j = 0; j < 8; ++j) acc[aa][i][j] += av[aa][i] * tt[j];
    }
  }

  // ||.||^2 contribution (core region only)
  float ss = 0.f;
#pragma unroll
  for (int aa = 0; aa < 2; ++aa)
#pragma unroll
    for (int i = 0; i < 4; ++i)
#pragma unroll
      for (int j = 0; j < 8; ++j) ss += acc[aa][i][j] * acc[aa][i][j];
#pragma unroll
  for (int off = 32; off > 0; off >>= 1) ss += __shfl_down(ss, off);
  if ((tid & 63) == 0) atomicAdd(&normsq[b], ss);

  // write via LDS for coalesced 128-float rows
  for (int aa = 0; aa < 2; ++aa) {
    const int a = 1 + 2 * p + aa;
    float* Fb = F + ((size_t)b * AE + a) * PLANE;
#pragma unroll
    for (int g = 0; g < 4; ++g) {
      __syncthreads();
      *(float4*)&sOut[tv][8 * tw] =
          make_float4(acc[aa][g][0], acc[aa][g][1], acc[aa][g][2], acc[aa][g][3]);
      *(float4*)&sOut[tv][8 * tw + 4] =
          make_float4(acc[aa][g][4], acc[aa][g][5], acc[aa][g][6], acc[aa][g][7]);
      __syncthreads();
#pragma unroll
      for (int r = 0; r < 8; ++r) {
        const int e = tid + 256 * r;        // < 2048
        const int row = e >> 7, wi = e & 127;
        Fb[(size_t)(1 + 4 * row + g) * TE + 1 + wi] = sOut[row][wi];
      }
    }
  }
}

// ---------------- plane a=0: fusion[b][0][v][w] = sum_s v'*t' ----------------
__global__ __launch_bounds__(256) void k_pa(
    const float* __restrict__ vision, const float* __restrict__ text,
    float* __restrict__ F, float* __restrict__ normsq)
{
  const int b = blockIdx.x;
  const int tid = threadIdx.x;
  const int tw = tid & 15, tv = tid >> 4;
  __shared__ float sv[32][80];
  __shared__ float st[32][144];
  float acc[5][9];
#pragma unroll
  for (int i = 0; i < 5; ++i)
#pragma unroll
    for (int j = 0; j < 9; ++j) acc[i][j] = 0.f;

  for (int c = 0; c < 4; ++c) {
    const int s0 = 32 * c;
    __syncthreads();
    const float* vbase = &vision[((size_t)(b * SS + s0)) * 64];
#pragma unroll
    for (int r = 0; r < 8; ++r) {
      const int e = tid + 256 * r;          // < 2048
      sv[e >> 6][(e & 63) + 1] = vbase[e];
    }
    const float* tbase = &text[((size_t)(b * SS + s0)) * 128];
#pragma unroll
    for (int r = 0; r < 16; ++r) {
      const int e = tid + 256 * r;          // < 4096
      st[e >> 7][(e & 127) + 1] = tbase[e];
    }
    if (tid < 32) { sv[tid][0] = 1.f; st[tid][0] = 1.f; }
    __syncthreads();
    for (int s = 0; s < 32; ++s) {
      float vr[5], tr[9];
#pragma unroll
      for (int i = 0; i < 5; ++i) {
        const int vx = tv + 16 * i;
        vr[i] = (vx < VE) ? sv[s][vx] : 0.f;
      }
#pragma unroll
      for (int j = 0; j < 9; ++j) {
        const int wx = tw + 16 * j;
        tr[j] = (wx < TE) ? st[s][wx] : 0.f;
      }
#pragma unroll
      for (int i = 0; i < 5; ++i)
#pragma unroll
        for (int j = 0; j < 9; ++j) acc[i][j] += vr[i] * tr[j];
    }
  }
  float* Fb = F + (size_t)b * AE * PLANE;   // a = 0
  float ss = 0.f;
#pragma unroll
  for (int i = 0; i < 5; ++i) {
    const int v = tv + 16 * i;
    if (v < VE) {
#pragma unroll
      for (int j = 0; j < 9; ++j) {
        const int w = tw + 16 * j;
        if (w < TE) {
          const float m = acc[i][j];
          Fb[(size_t)v * TE + w] = m;
          ss += m * m;
        }
      }
    }
  }
#pragma unroll
  for (int off = 32; off > 0; off >>= 1) ss += __shfl_down(ss, off);
  if ((tid & 63) == 0) atomicAdd(&normsq[b], ss);
}

// ---------------- plane v=0: fusion[b][a][0][w] = sum_s a'*t', a>=1 ----------------
__global__ __launch_bounds__(256) void k_pv(
    const float* __restrict__ audio, const float* __restrict__ text,
    float* __restrict__ F, float* __restrict__ normsq)
{
  const int b = blockIdx.x;
  const int tid = threadIdx.x;
  const int tw = tid & 15, tv = tid >> 4;
  __shared__ float sa[32][64];
  __shared__ float st[32][144];
  float acc[4][9];
#pragma unroll
  for (int i = 0; i < 4; ++i)
#pragma unroll
    for (int j = 0; j < 9; ++j) acc[i][j] = 0.f;

  for (int c = 0; c < 4; ++c) {
    const int s0 = 32 * c;
    __syncthreads();
    const float* abase = &audio[((size_t)(b * SS + s0)) * 64];
#pragma unroll
    for (int r = 0; r < 8; ++r) {
      const int e = tid + 256 * r;
      sa[e >> 6][e & 63] = abase[e];
    }
    const float* tbase = &text[((size_t)(b * SS + s0)) * 128];
#pragma unroll
    for (int r = 0; r < 16; ++r) {
      const int e = tid + 256 * r;
      st[e >> 7][(e & 127) + 1] = tbase[e];
    }
    if (tid < 32) st[tid][0] = 1.f;
    __syncthreads();
    for (int s = 0; s < 32; ++s) {
      float ar[4], tr[9];
#pragma unroll
      for (int i = 0; i < 4; ++i) ar[i] = sa[s][tv + 16 * i];
#pragma unroll
      for (int j = 0; j < 9; ++j) {
        const int wx = tw + 16 * j;
        tr[j] = (wx < TE) ? st[s][wx] : 0.f;
      }
#pragma unroll
      for (int i = 0; i < 4; ++i)
#pragma unroll
        for (int j = 0; j < 9; ++j) acc[i][j] += ar[i] * tr[j];
    }
  }
  float ss = 0.f;
#pragma unroll
  for (int i = 0; i < 4; ++i) {
    const int a = 1 + tv + 16 * i;
    float* Fb = F + ((size_t)b * AE + a) * PLANE;   // v = 0
#pragma unroll
    for (int j = 0; j < 9; ++j) {
      const int w = tw + 16 * j;
      if (w < TE) {
        const float m = acc[i][j];
        Fb[w] = m;
        ss += m * m;
      }
    }
  }
#pragma unroll
  for (int off = 32; off > 0; off >>= 1) ss += __shfl_down(ss, off);
  if ((tid & 63) == 0) atomicAdd(&normsq[b], ss);
}

// ---------------- plane w=0: fusion[b][a][v][0] = sum_s a'*v', a,v>=1 ----------------
__global__ __launch_bounds__(256) void k_pw(
    const float* __restrict__ audio, const float* __restrict__ vision,
    float* __restrict__ F, float* __restrict__ normsq)
{
  const int b = blockIdx.x;
  const int tid = threadIdx.x;
  const int tw = tid & 15, tv = tid >> 4;
  __shared__ float sa[32][64];
  __shared__ float sv[32][64];
  float acc[4][4];
#pragma unroll
  for (int i = 0; i < 4; ++i)
#pragma unroll
    for (int j = 0; j < 4; ++j) acc[i][j] = 0.f;

  for (int c = 0; c < 4; ++c) {
    const int s0 = 32 * c;
    __syncthreads();
    const float* abase = &audio[((size_t)(b * SS + s0)) * 64];
    const float* vbase = &vision[((size_t)(b * SS + s0)) * 64];
#pragma unroll
    for (int r = 0; r < 8; ++r) {
      const int e = tid + 256 * r;
      sa[e >> 6][e & 63] = abase[e];
      sv[e >> 6][e & 63] = vbase[e];
    }
    __syncthreads();
    for (int s = 0; s < 32; ++s) {
      float ar[4], vr[4];
#pragma unroll
      for (int i = 0; i < 4; ++i) ar[i] = sa[s][tv + 16 * i];
#pragma unroll
      for (int j = 0; j < 4; ++j) vr[j] = sv[s][tw + 16 * j];
#pragma unroll
      for (int i = 0; i < 4; ++i)
#pragma unroll
        for (int j = 0; j < 4; ++j) acc[i][j] += ar[i] * vr[j];
    }
  }
  float ss = 0.f;
#pragma unroll
  for (int i = 0; i < 4; ++i) {
    const int a = 1 + tv + 16 * i;
    float* Fb = F + ((size_t)b * AE + a) * PLANE;
#pragma unroll
    for (int j = 0; j < 4; ++j) {
      const int v = 1 + tw + 16 * j;
      const float m = acc[i][j];
      Fb[(size_t)v * TE] = m;                       // w = 0
      ss += m * m;
    }
  }
#pragma unroll
  for (int off = 32; off > 0; off >>= 1) ss += __shfl_down(ss, off);
  if ((tid & 63) == 0) atomicAdd(&normsq[b], ss);
}

// ---------------- deep-K GEMM: y1pre[b][p] += W1[p][k]*F[b][k] ----------------
#define KSPAN 1024
#define KT 32
__global__ __launch_bounds__(256) void k_gemm(
    const float* __restrict__ W1, const float* __restrict__ F,
    float* __restrict__ y1pre)
{
  const size_t k0 = (size_t)blockIdx.x * KSPAN;
  const int tid = threadIdx.x;
  const int tb = tid & 15, tp = tid >> 4;
  const int srow = tid >> 5, skk = tid & 31;   // staging coords: 2 rows/wave, 32 k

  __shared__ float sW[KT][132];
  __shared__ float sF[KT][132];

  float acc[8][8];
#pragma unroll
  for (int i = 0; i < 8; ++i)
#pragma unroll
    for (int j = 0; j < 8; ++j) acc[i][j] = 0.f;

  float wv[16], fv[16];
#pragma unroll
  for (int r = 0; r < 16; ++r) {     // prefetch iter 0: rows srow+8r, col skk
    const int row = srow + 8 * r;
    const size_t k = k0 + skk;
    const bool ok = k < FUSED;
    wv[r] = ok ? W1[(size_t)row * FUSED + k] : 0.f;
    fv[r] = ok ? F[(size_t)row * FUSED + k] : 0.f;
  }

  const int NIT = KSPAN / KT;       // 32
  for (int it = 0; it < NIT; ++it) {
    __syncthreads();
#pragma unroll
    for (int r = 0; r < 16; ++r) {
      const int row = srow + 8 * r;
      sW[skk][row] = wv[r];
      sF[skk][row] = fv[r];
    }
    __syncthreads();
    if (it + 1 < NIT) {
      const size_t kb = k0 + (size_t)(it + 1) * KT;
#pragma unroll
      for (int r = 0; r < 16; ++r) {
        const int row = srow + 8 * r;
        const size_t k = kb + skk;
        const bool ok = k < FUSED;
        wv[r] = ok ? W1[(size_t)row * FUSED + k] : 0.f;
        fv[r] = ok ? F[(size_t)row * FUSED + k] : 0.f;
      }
    }
#pragma unroll
    for (int kk = 0; kk < KT; ++kk) {
      const float4 w0 = *(const float4*)&sW[kk][8 * tp];
      const float4 w1 = *(const float4*)&sW[kk][8 * tp + 4];
      const float4 f0 = *(const float4*)&sF[kk][8 * tb];
      const float4 f1 = *(const float4*)&sF[kk][8 * tb + 4];
      const float wr[8] = {w0.x, w0.y, w0.z, w0.w, w1.x, w1.y, w1.z, w1.w};
      const float fr[8] = {f0.x, f0.y, f0.z, f0.w, f1.x, f1.y, f1.z, f1.w};
#pragma unroll
      for (int i = 0; i < 8; ++i)
#pragma unroll
        for (int j = 0; j < 8; ++j) acc[i][j] += wr[i] * fr[j];
    }
  }

  // static, fully-unrolled drain — NO runtime indexing into acc (rule #20)
#pragma unroll
  for (int j = 0; j < 8; ++j)
#pragma unroll
    for (int i = 0; i < 8; ++i)
      atomicAdd(&y1pre[(size_t)(8 * tb + j) * PFD + 8 * tp + i], acc[i][j]);
}

// ---------------- finalize: MLP per batch ----------------
__global__ __launch_bounds__(128) void k_final(
    const float* __restrict__ y1pre, const float* __restrict__ b1,
    const float* __restrict__ W2, const float* __restrict__ b2,
    const float* __restrict__ W3, const float* __restrict__ b3,
    float* __restrict__ out)
{
  const int b = blockIdx.x, p = threadIdx.x;
  __shared__ float y1[PFD];
  __shared__ float red[PFD];
  y1[p] = fmaxf(y1pre[(size_t)b * PFD + p] + b1[p], 0.f);
  __syncthreads();
  float s = b2[p];
  for (int k = 0; k < PFD; ++k) s += y1[k] * W2[p * PFD + k];
  const float y2 = fmaxf(s, 0.f);
  red[p] = y2 * W3[p];
  __syncthreads();
  for (int off = 64; off > 0; off >>= 1) {
    if (p < off) red[p] += red[p + off];
    __syncthreads();
  }
  if (p == 0) {
    const float x = red[0] + b3[0];
    out[b] = 6.f / (1.f + expf(-x)) - 3.f;
  }
}

__global__ __launch_bounds__(128) void k_reg(const float* __restrict__ normsq,
                                             float* __restrict__ out)
{
  const int t = threadIdx.x;
  __shared__ float red[BB];
  red[t] = sqrtf(normsq[t]);
  __syncthreads();
  for (int off = 64; off > 0; off >>= 1) {
    if (t < off) red[t] += red[t + off];
    __syncthreads();
  }
  // tmp = sqrt(64*64*128/128) = 64 exactly; mean over B
  if (t == 0) out[BB] = 64.f * red[0] / (float)BB;
}

extern "C" void kernel_launch(void* const* d_in, const int* in_sizes, int n_in,
                              void* d_out, int out_size, void* d_ws, size_t ws_size,
                              hipStream_t stream) {
  const float* audio  = (const float*)d_in[0];
  const float* vision = (const float*)d_in[1];
  const float* text   = (const float*)d_in[2];
  const float* W1     = (const float*)d_in[3];
  const float* b1     = (const float*)d_in[4];
  const float* W2     = (const float*)d_in[5];
  const float* b2     = (const float*)d_in[6];
  const float* W3     = (const float*)d_in[7];
  const float* b3     = (const float*)d_in[8];
  float* out = (float*)d_out;

  // ws layout (known-safe bound from round 1: ws >= 131072 + 279,052,800 B):
  // [y1pre 128*128][normsq 128] ... F (full fusion, fp32) at +128 KB
  float* y1pre  = (float*)d_ws;
  float* normsq = y1pre + BB * PFD;
  float* F = (float*)((char*)d_ws + 131072);

  k_zero<<<65, 256, 0, stream>>>(y1pre, BB * PFD + BB);

  k_core<<<dim3(BB, 32), 256, 0, stream>>>(audio, vision, text, F, normsq);
  k_pa<<<BB, 256, 0, stream>>>(vision, text, F, normsq);
  k_pv<<<BB, 256, 0, stream>>>(audio, text, F, normsq);
  k_pw<<<BB, 256, 0, stream>>>(audio, vision, F, normsq);

  const int nb = (int)((FUSED + KSPAN - 1) / KSPAN);   // 533
  k_gemm<<<nb, 256, 0, stream>>>(W1, F, y1pre);

  k_final<<<BB, PFD, 0, stream>>>(y1pre, b1, W2, b2, W3, b3, out);
  k_reg<<<1, BB, 0, stream>>>(normsq, out);
}

// Round 4
// 701.892 us; speedup vs baseline: 6.0376x; 1.6766x over previous
//
#include <hip/hip_runtime.h>
#include <math.h>

#define BB 128
#define SS 128
#define AE 65
#define VE 65
#define TE 129
#define PFD 128
#define FUSED 545025UL
#define FUSEDI 545025
#define FUSED_P 545792UL   // padded f16 row stride = 533*1024 (16B aligned)
#define PLANE (VE * TE)    // 8385
#define KSPAN 1024
#define NSTEP 32

typedef _Float16 half8 __attribute__((ext_vector_type(8)));
typedef float f32x16 __attribute__((ext_vector_type(16)));

__device__ __forceinline__ void gll4(const void* g, void* l) {
  __builtin_amdgcn_global_load_lds((const __attribute__((address_space(1))) void*)g,
                                   (__attribute__((address_space(3))) void*)l, 4, 0, 0);
}
__device__ __forceinline__ void gll16(const void* g, void* l) {
  __builtin_amdgcn_global_load_lds((const __attribute__((address_space(1))) void*)g,
                                   (__attribute__((address_space(3))) void*)l, 16, 0, 0);
}

// ---------------- zero-init accumulators ----------------
__global__ __launch_bounds__(256) void k_zero(float* __restrict__ p, int n) {
  int i = blockIdx.x * 256 + threadIdx.x;
  if (i < n) p[i] = 0.f;
}

// zero the f16 row padding [FUSED, FUSED_P) for each of the 128 rows
__global__ __launch_bounds__(256) void k_fpad(_Float16* __restrict__ Fh) {
  const int b = blockIdx.x;
  for (int i = threadIdx.x; i < (int)(FUSED_P - FUSED); i += 256)
    Fh[(size_t)b * FUSED_P + FUSED + i] = (_Float16)0.f;
}

// ---------------- core: fusion[b][a][v][w], a,v>=1, w>=1 (fp32 compute, f16 store) ---
__global__ __launch_bounds__(256) void k_core(
    const float* __restrict__ audio, const float* __restrict__ vision,
    const float* __restrict__ text, _Float16* __restrict__ Fh,
    float* __restrict__ normsq)
{
  const int b = blockIdx.x;
  const int p = blockIdx.y;
  const int tid = threadIdx.x;
  const int tw = tid & 15, tv = tid >> 4;

  __shared__ float sA[2][16];
  __shared__ float sAV[16][2][64];
  __shared__ float sT[16][192];
  __shared__ float sOut[16][132];

  float acc[2][4][8];
#pragma unroll
  for (int aa = 0; aa < 2; ++aa)
#pragma unroll
    for (int i = 0; i < 4; ++i)
#pragma unroll
      for (int j = 0; j < 8; ++j) acc[aa][i][j] = 0.f;

  for (int c = 0; c < 8; ++c) {
    const int s0 = c * 16;
    __syncthreads();
    if (tid < 16) {
      const float2 a2 = *(const float2*)&audio[((size_t)(b * SS + s0 + tid)) * 64 + 2 * p];
      sA[0][tid] = a2.x;
      sA[1][tid] = a2.y;
    }
    __syncthreads();
    const float* vbase = &vision[((size_t)(b * SS + s0)) * 64];
#pragma unroll
    for (int r = 0; r < 4; ++r) {
      const int e = tid + 256 * r;
      const int s = e >> 6, v = e & 63;
      const float vv = vbase[e];
      sAV[s][0][v] = sA[0][s] * vv;
      sAV[s][1][v] = sA[1][s] * vv;
    }
    const float* tbase = &text[((size_t)(b * SS + s0)) * 128];
#pragma unroll
    for (int r = 0; r < 8; ++r) {
      const int e = tid + 256 * r;
      const int s = e >> 7, w = e & 127;
      sT[s][12 * (w >> 3) + (w & 7)] = tbase[e];
    }
    __syncthreads();
#pragma unroll
    for (int s = 0; s < 16; ++s) {
      const float4 a0 = *(const float4*)&sAV[s][0][4 * tv];
      const float4 a1 = *(const float4*)&sAV[s][1][4 * tv];
      const float4 t0 = *(const float4*)&sT[s][12 * tw];
      const float4 t1 = *(const float4*)&sT[s][12 * tw + 4];
      const float av[2][4] = {{a0.x, a0.y, a0.z, a0.w}, {a1.x, a1.y, a1.z, a1.w}};
      const float tt[8] = {t0.x, t0.y, t0.z, t0.w, t1.x, t1.y, t1.z, t1.w};
#pragma unroll
      for (int aa = 0; aa < 2; ++aa)
#pragma unroll
        for (int i = 0; i < 4; ++i)
#pragma unroll
          for (int j = 0; j < 8; ++j) acc[aa][i][j] += av[aa][i] * tt[j];
    }
  }

  float ss = 0.f;
#pragma unroll
  for (int aa = 0; aa < 2; ++aa)
#pragma unroll
    for (int i = 0; i < 4; ++i)
#pragma unroll
      for (int j = 0; j < 8; ++j) ss += acc[aa][i][j] * acc[aa][i][j];
#pragma unroll
  for (int off = 32; off > 0; off >>= 1) ss += __shfl_down(ss, off);
  if ((tid & 63) == 0) atomicAdd(&normsq[b], ss);

  for (int aa = 0; aa < 2; ++aa) {
    const int a = 1 + 2 * p + aa;
    _Float16* Fb = Fh + (size_t)b * FUSED_P + (size_t)a * PLANE;
#pragma unroll
    for (int g = 0; g < 4; ++g) {
      __syncthreads();
      *(float4*)&sOut[tv][8 * tw] =
          make_float4(acc[aa][g][0], acc[aa][g][1], acc[aa][g][2], acc[aa][g][3]);
      *(float4*)&sOut[tv][8 * tw + 4] =
          make_float4(acc[aa][g][4], acc[aa][g][5], acc[aa][g][6], acc[aa][g][7]);
      __syncthreads();
#pragma unroll
      for (int r = 0; r < 8; ++r) {
        const int e = tid + 256 * r;
        const int row = e >> 7, wi = e & 127;
        Fb[(size_t)(1 + 4 * row + g) * TE + 1 + wi] = (_Float16)sOut[row][wi];
      }
    }
  }
}

// ---------------- plane a=0 ----------------
__global__ __launch_bounds__(256) void k_pa(
    const float* __restrict__ vision, const float* __restrict__ text,
    _Float16* __restrict__ Fh, float* __restrict__ normsq)
{
  const int b = blockIdx.x;
  const int tid = threadIdx.x;
  const int tw = tid & 15, tv = tid >> 4;
  __shared__ float sv[32][80];
  __shared__ float st[32][144];
  float acc[5][9];
#pragma unroll
  for (int i = 0; i < 5; ++i)
#pragma unroll
    for (int j = 0; j < 9; ++j) acc[i][j] = 0.f;

  for (int c = 0; c < 4; ++c) {
    const int s0 = 32 * c;
    __syncthreads();
    const float* vbase = &vision[((size_t)(b * SS + s0)) * 64];
#pragma unroll
    for (int r = 0; r < 8; ++r) {
      const int e = tid + 256 * r;
      sv[e >> 6][(e & 63) + 1] = vbase[e];
    }
    const float* tbase = &text[((size_t)(b * SS + s0)) * 128];
#pragma unroll
    for (int r = 0; r < 16; ++r) {
      const int e = tid + 256 * r;
      st[e >> 7][(e & 127) + 1] = tbase[e];
    }
    if (tid < 32) { sv[tid][0] = 1.f; st[tid][0] = 1.f; }
    __syncthreads();
    for (int s = 0; s < 32; ++s) {
      float vr[5], tr[9];
#pragma unroll
      for (int i = 0; i < 5; ++i) {
        const int vx = tv + 16 * i;
        vr[i] = (vx < VE) ? sv[s][vx] : 0.f;
      }
#pragma unroll
      for (int j = 0; j < 9; ++j) {
        const int wx = tw + 16 * j;
        tr[j] = (wx < TE) ? st[s][wx] : 0.f;
      }
#pragma unroll
      for (int i = 0; i < 5; ++i)
#pragma unroll
        for (int j = 0; j < 9; ++j) acc[i][j] += vr[i] * tr[j];
    }
  }
  _Float16* Fb = Fh + (size_t)b * FUSED_P;   // a = 0
  float ss = 0.f;
#pragma unroll
  for (int i = 0; i < 5; ++i) {
    const int v = tv + 16 * i;
    if (v < VE) {
#pragma unroll
      for (int j = 0; j < 9; ++j) {
        const int w = tw + 16 * j;
        if (w < TE) {
          const float m = acc[i][j];
          Fb[(size_t)v * TE + w] = (_Float16)m;
          ss += m * m;
        }
      }
    }
  }
#pragma unroll
  for (int off = 32; off > 0; off >>= 1) ss += __shfl_down(ss, off);
  if ((tid & 63) == 0) atomicAdd(&normsq[b], ss);
}

// ---------------- plane v=0 ----------------
__global__ __launch_bounds__(256) void k_pv(
    const float* __restrict__ audio, const float* __restrict__ text,
    _Float16* __restrict__ Fh, float* __restrict__ normsq)
{
  const int b = blockIdx.x;
  const int tid = threadIdx.x;
  const int tw = tid & 15, tv = tid >> 4;
  __shared__ float sa[32][64];
  __shared__ float st[32][144];
  float acc[4][9];
#pragma unroll
  for (int i = 0; i < 4; ++i)
#pragma unroll
    for (int j = 0; j < 9; ++j) acc[i][j] = 0.f;

  for (int c = 0; c < 4; ++c) {
    const int s0 = 32 * c;
    __syncthreads();
    const float* abase = &audio[((size_t)(b * SS + s0)) * 64];
#pragma unroll
    for (int r = 0; r < 8; ++r) {
      const int e = tid + 256 * r;
      sa[e >> 6][e & 63] = abase[e];
    }
    const float* tbase = &text[((size_t)(b * SS + s0)) * 128];
#pragma unroll
    for (int r = 0; r < 16; ++r) {
      const int e = tid + 256 * r;
      st[e >> 7][(e & 127) + 1] = tbase[e];
    }
    if (tid < 32) st[tid][0] = 1.f;
    __syncthreads();
    for (int s = 0; s < 32; ++s) {
      float ar[4], tr[9];
#pragma unroll
      for (int i = 0; i < 4; ++i) ar[i] = sa[s][tv + 16 * i];
#pragma unroll
      for (int j = 0; j < 9; ++j) {
        const int wx = tw + 16 * j;
        tr[j] = (wx < TE) ? st[s][wx] : 0.f;
      }
#pragma unroll
      for (int i = 0; i < 4; ++i)
#pragma unroll
        for (int j = 0; j < 9; ++j) acc[i][j] += ar[i] * tr[j];
    }
  }
  float ss = 0.f;
#pragma unroll
  for (int i = 0; i < 4; ++i) {
    const int a = 1 + tv + 16 * i;
    _Float16* Fb = Fh + (size_t)b * FUSED_P + (size_t)a * PLANE;   // v = 0
#pragma unroll
    for (int j = 0; j < 9; ++j) {
      const int w = tw + 16 * j;
      if (w < TE) {
        const float m = acc[i][j];
        Fb[w] = (_Float16)m;
        ss += m * m;
      }
    }
  }
#pragma unroll
  for (int off = 32; off > 0; off >>= 1) ss += __shfl_down(ss, off);
  if ((tid & 63) == 0) atomicAdd(&normsq[b], ss);
}

// ---------------- plane w=0 ----------------
__global__ __launch_bounds__(256) void k_pw(
    const float* __restrict__ audio, const float* __restrict__ vision,
    _Float16* __restrict__ Fh, float* __restrict__ normsq)
{
  const int b = blockIdx.x;
  const int tid = threadIdx.x;
  const int tw = tid & 15, tv = tid >> 4;
  __shared__ float sa[32][64];
  __shared__ float sv[32][64];
  float acc[4][4];
#pragma unroll
  for (int i = 0; i < 4; ++i)
#pragma unroll
    for (int j = 0; j < 4; ++j) acc[i][j] = 0.f;

  for (int c = 0; c < 4; ++c) {
    const int s0 = 32 * c;
    __syncthreads();
    const float* abase = &audio[((size_t)(b * SS + s0)) * 64];
    const float* vbase = &vision[((size_t)(b * SS + s0)) * 64];
#pragma unroll
    for (int r = 0; r < 8; ++r) {
      const int e = tid + 256 * r;
      sa[e >> 6][e & 63] = abase[e];
      sv[e >> 6][e & 63] = vbase[e];
    }
    __syncthreads();
    for (int s = 0; s < 32; ++s) {
      float ar[4], vr[4];
#pragma unroll
      for (int i = 0; i < 4; ++i) ar[i] = sa[s][tv + 16 * i];
#pragma unroll
      for (int j = 0; j < 4; ++j) vr[j] = sv[s][tw + 16 * j];
#pragma unroll
      for (int i = 0; i < 4; ++i)
#pragma unroll
        for (int j = 0; j < 4; ++j) acc[i][j] += ar[i] * vr[j];
    }
  }
  float ss = 0.f;
#pragma unroll
  for (int i = 0; i < 4; ++i) {
    const int a = 1 + tv + 16 * i;
    _Float16* Fb = Fh + (size_t)b * FUSED_P + (size_t)a * PLANE;
#pragma unroll
    for (int j = 0; j < 4; ++j) {
      const int v = 1 + tw + 16 * j;
      const float m = acc[i][j];
      Fb[(size_t)v * TE] = (_Float16)m;                       // w = 0
      ss += m * m;
    }
  }
#pragma unroll
  for (int off = 32; off > 0; off >>= 1) ss += __shfl_down(ss, off);
  if ((tid & 63) == 0) atomicAdd(&normsq[b], ss);
}

// ---------------- deep-K MFMA GEMM: y1pre[b][p] += W1[p][k]*Fh[b][k] ----------------
// grid 533 (K-split). 4 waves; wave w owns p-rows [32w,32w+32), all 128 b.
// LDS tiles: sW fp32 [128 p][32 k] (chunk16B ^= r&7), sF f16 [128 b][32 k] (chunk ^= (r>>1)&3)
__global__ __launch_bounds__(256) void k_gemm(
    const float* __restrict__ W1, const _Float16* __restrict__ Fh,
    float* __restrict__ y1pre)
{
  __shared__ float sW[2][128 * 32];       // 2 x 16 KB
  __shared__ _Float16 sF[2][128 * 32];    // 2 x 8 KB

  const int tid = threadIdx.x;
  const int wv = tid >> 6, ln = tid & 63;
  const int lb = ln & 31, hb = ln >> 5;
  const int k0 = blockIdx.x * KSPAN;

  f32x16 acc0 = {}, acc1 = {}, acc2 = {}, acc3 = {};

  // ---- staging macro (per K32-step) ----
#define STAGE(BUF, KC)                                                          \
  {                                                                             \
    const int kc_ = (KC);                                                       \
    _Pragma("unroll")                                                           \
    for (int n = 0; n < 16; ++n) {                                              \
      const int slab = (wv << 4) + n;                                           \
      const int r = (slab << 1) + hb;                                           \
      const int wir = ln & 31;                                                  \
      const int cp = wir >> 2, wic = wir & 3;                                   \
      int kidx = kc_ + ((cp ^ (r & 7)) << 2) + wic;                             \
      kidx = kidx < FUSEDI ? kidx : (FUSEDI - 1);                               \
      gll4(&W1[(size_t)r * FUSED + kidx], (char*)&sW[BUF][0] + (slab << 8));    \
    }                                                                           \
    _Pragma("unroll")                                                           \
    for (int n = 0; n < 2; ++n) {                                               \
      const int slab = (wv << 1) + n;                                           \
      const int r = (slab << 4) + (ln >> 2);                                    \
      const int cp = ln & 3;                                                    \
      const int clog = cp ^ ((r >> 1) & 3);                                     \
      gll16((const char*)Fh + (((size_t)r * FUSED_P + kc_) << 1) + (clog << 4), \
            (char*)&sF[BUF][0] + (slab << 10));                                 \
    }                                                                           \
  }

  STAGE(0, k0);
  __syncthreads();   // drains vmcnt, all LDS visible

  int buf = 0;
  const int ra = (wv << 5) + lb;
  const int rsw = ra & 7;
  const int csw = (lb >> 1) & 3;   // F swizzle key (same for all b-tiles)

  for (int step = 0; step < NSTEP; ++step) {
    if (step + 1 < NSTEP) STAGE(buf ^ 1, k0 + (step + 1) * 32);

    const float* sWb = &sW[buf][0];
    const _Float16* sFb = &sF[buf][0];
#pragma unroll
    for (int ks = 0; ks < 2; ++ks) {
      const int c0 = (ks << 2) + (hb << 1);
      const float4 x0 = *(const float4*)&sWb[(ra << 5) + ((c0 ^ rsw) << 2)];
      const float4 x1 = *(const float4*)&sWb[(ra << 5) + (((c0 + 1) ^ rsw) << 2)];
      half8 af;
      af[0] = (_Float16)x0.x; af[1] = (_Float16)x0.y;
      af[2] = (_Float16)x0.z; af[3] = (_Float16)x0.w;
      af[4] = (_Float16)x1.x; af[5] = (_Float16)x1.y;
      af[6] = (_Float16)x1.z; af[7] = (_Float16)x1.w;
      const int cl = (ks << 1) + hb;
      const int cpb = (cl ^ csw) << 3;
      {
        const half8 bf = *(const half8*)&sFb[(lb << 5) + cpb];
        acc0 = __builtin_amdgcn_mfma_f32_32x32x16_f16(af, bf, acc0, 0, 0, 0);
      }
      {
        const half8 bf = *(const half8*)&sFb[((32 + lb) << 5) + cpb];
        acc1 = __builtin_amdgcn_mfma_f32_32x32x16_f16(af, bf, acc1, 0, 0, 0);
      }
      {
        const half8 bf = *(const half8*)&sFb[((64 + lb) << 5) + cpb];
        acc2 = __builtin_amdgcn_mfma_f32_32x32x16_f16(af, bf, acc2, 0, 0, 0);
      }
      {
        const half8 bf = *(const half8*)&sFb[((96 + lb) << 5) + cpb];
        acc3 = __builtin_amdgcn_mfma_f32_32x32x16_f16(af, bf, acc3, 0, 0, 0);
      }
    }
    __syncthreads();   // drains this step's gll (next buf) + read fence
    buf ^= 1;
  }
#undef STAGE

  // drain: C layout col=lane&31 (b-local), row=(reg&3)+8*(reg>>2)+4*(lane>>5) (p-local)
#pragma unroll
  for (int reg = 0; reg < 16; ++reg) {
    const int prow = (reg & 3) + 8 * (reg >> 2) + 4 * hb;
    const int p = (wv << 5) + prow;
    atomicAdd(&y1pre[(size_t)(lb) * PFD + p], acc0[reg]);
    atomicAdd(&y1pre[(size_t)(32 + lb) * PFD + p], acc1[reg]);
    atomicAdd(&y1pre[(size_t)(64 + lb) * PFD + p], acc2[reg]);
    atomicAdd(&y1pre[(size_t)(96 + lb) * PFD + p], acc3[reg]);
  }
}

// ---------------- finalize: MLP per batch ----------------
__global__ __launch_bounds__(128) void k_final(
    const float* __restrict__ y1pre, const float* __restrict__ b1,
    const float* __restrict__ W2, const float* __restrict__ b2,
    const float* __restrict__ W3, const float* __restrict__ b3,
    float* __restrict__ out)
{
  const int b = blockIdx.x, p = threadIdx.x;
  __shared__ float y1[PFD];
  __shared__ float red[PFD];
  y1[p] = fmaxf(y1pre[(size_t)b * PFD + p] + b1[p], 0.f);
  __syncthreads();
  float s = b2[p];
  for (int k = 0; k < PFD; ++k) s += y1[k] * W2[p * PFD + k];
  const float y2 = fmaxf(s, 0.f);
  red[p] = y2 * W3[p];
  __syncthreads();
  for (int off = 64; off > 0; off >>= 1) {
    if (p < off) red[p] += red[p + off];
    __syncthreads();
  }
  if (p == 0) {
    const float x = red[0] + b3[0];
    out[b] = 6.f / (1.f + expf(-x)) - 3.f;
  }
}

__global__ __launch_bounds__(128) void k_reg(const float* __restrict__ normsq,
                                             float* __restrict__ out)
{
  const int t = threadIdx.x;
  __shared__ float red[BB];
  red[t] = sqrtf(normsq[t]);
  __syncthreads();
  for (int off = 64; off > 0; off >>= 1) {
    if (t < off) red[t] += red[t + off];
    __syncthreads();
  }
  if (t == 0) out[BB] = 64.f * red[0] / (float)BB;
}

extern "C" void kernel_launch(void* const* d_in, const int* in_sizes, int n_in,
                              void* d_out, int out_size, void* d_ws, size_t ws_size,
                              hipStream_t stream) {
  const float* audio  = (const float*)d_in[0];
  const float* vision = (const float*)d_in[1];
  const float* text   = (const float*)d_in[2];
  const float* W1     = (const float*)d_in[3];
  const float* b1     = (const float*)d_in[4];
  const float* W2     = (const float*)d_in[5];
  const float* b2     = (const float*)d_in[6];
  const float* W3     = (const float*)d_in[7];
  const float* b3     = (const float*)d_in[8];
  float* out = (float*)d_out;

  // ws layout (proven bound ws >= 279,183,872 B):
  // [y1pre 64KB][normsq 512B] ... Fh (f16, padded rows) at +128 KB: 139,722,752 B
  float* y1pre  = (float*)d_ws;
  float* normsq = y1pre + BB * PFD;
  _Float16* Fh = (_Float16*)((char*)d_ws + 131072);

  k_zero<<<65, 256, 0, stream>>>(y1pre, BB * PFD + BB);
  k_fpad<<<BB, 256, 0, stream>>>(Fh);

  k_core<<<dim3(BB, 32), 256, 0, stream>>>(audio, vision, text, Fh, normsq);
  k_pa<<<BB, 256, 0, stream>>>(vision, text, Fh, normsq);
  k_pv<<<BB, 256, 0, stream>>>(audio, text, Fh, normsq);
  k_pw<<<BB, 256, 0, stream>>>(audio, vision, Fh, normsq);

  k_gemm<<<(int)((FUSED + KSPAN - 1) / KSPAN), 256, 0, stream>>>(W1, Fh, y1pre);

  k_final<<<BB, PFD, 0, stream>>>(y1pre, b1, W2, b2, W3, b3, out);
  k_reg<<<1, BB, 0, stream>>>(normsq, out);
}